// Round 5
// baseline (283.082 us; speedup 1.0000x reference)
//
#include <hip/hip_runtime.h>
#include <math.h>

#define BB 32
#define SS 4096
#define DD 256
#define DAA 128
#define DPP 64
#define CHUNKS 32
#define ROWS_PER_BLOCK (SS / CHUNKS)                     // 128
#define WAVES_PER_BLOCK 4
#define ROWS_PER_WAVE (ROWS_PER_BLOCK / WAVES_PER_BLOCK) // 32
#define BATCH 8
#define NBATCH (ROWS_PER_WAVE / BATCH)                   // 4
#define VH_SLICES 8
#define SLICE (DAA / VH_SLICES)                          // 16

// workspace layout (float elements)
#define WS_VHP  0                         // 8 x 256 partial vh
#define WS_VQP  (WS_VHP + VH_SLICES*DD)   // 8 x 256 partial vq
#define WS_VP   (WS_VQP + VH_SLICES*DD)   // 128: [vp1[64] | vp2[64]]
#define WS_BC   (WS_VP + 128)
#define WS_PART (WS_BC + 16)              // 16B-aligned
#define PART_STRIDE 258                   // [l, ctx[256], pad]

typedef float f4 __attribute__((ext_vector_type(4)));
typedef float f2 __attribute__((ext_vector_type(2)));

// ---------------------------------------------------------------------------
// Kernel 0: fold Wc into projection vectors. Blocks 0..7 each do a 16-row
// slice of the Wh/Wq dots; block 8 does vp1/vp2/bc. main sums the 8
// partials per lane.
// ---------------------------------------------------------------------------
__global__ void prep_kernel(const float* __restrict__ Wh,
                            const float* __restrict__ Wq,
                            const float* __restrict__ Wp1,
                            const float* __restrict__ Wp2,
                            const float* __restrict__ Wc,
                            const float* __restrict__ bc,
                            float* __restrict__ ws) {
    const int tid = threadIdx.x; // 256 threads
    const int blk = blockIdx.x;
    if (blk < VH_SLICES) {
        const int a0 = blk * SLICE;
        float vh = 0.f, vq = 0.f;
        #pragma unroll
        for (int i = 0; i < SLICE; ++i) {
            const int a = a0 + i;
            vh += Wh[a * DD + tid] * Wc[a];
            vq += Wq[a * DD + tid] * Wc[DAA + a];
        }
        ws[WS_VHP + blk * DD + tid] = vh;
        ws[WS_VQP + blk * DD + tid] = vq;
    } else {
        if (tid < DPP) {
            float vp1 = 0.f, vp2 = 0.f;
            for (int a = 0; a < DPP; ++a) {
                vp1 += Wp1[a * DPP + tid] * Wc[2 * DAA + a];
                vp2 += Wp2[a * DPP + tid] * Wc[2 * DAA + DPP + a];
            }
            ws[WS_VP + tid]       = vp1;   // lanes 0..31 read pairs from here
            ws[WS_VP + DPP + tid] = vp2;   // lanes 32..63 read pairs from here
        }
        if (tid == 0) ws[WS_BC] = bc[0];
    }
}

// ---------------------------------------------------------------------------
// Kernel 1: streaming tanh-softmax context.
// R10: the double-buffer hypothesis, tested for the first time SPILL-FREE.
// R2 (macros) and R3 (lambdas) both escaped the buffer arrays to scratch
// (VGPR=64, 77-94MB spill writeback) -- the pipeline was never actually
// measured. Here: literal straight-line code, arrays indexed only by
// constants inside #pragma-unroll loops (the exact form R4 proved
// promotes cleanly). (256,4): 128-VGPR budget, hand-counted peak live
// ~118 VGPR. Grid 1024 = exactly 4 blocks/CU, 16 waves/CU.
// Bulk reads nontemporal (R4-prev). No __threadfence (R5-prev).
// ---------------------------------------------------------------------------
__global__ __launch_bounds__(256, 4) void
main_kernel(const float* __restrict__ h,
            const float* __restrict__ q,
            const float* __restrict__ pf1,
            const float* __restrict__ pf2,
            float* __restrict__ ws) {
    const int c    = blockIdx.x;
    const int b    = blockIdx.y;
    const int tid  = threadIdx.x;
    const int wave = tid >> 6;
    const int lane = tid & 63;
    const int ll   = lane & 31;

    // per-lane constants: sum the 8 prep partials (L2-hot)
    f4 vh4 = {0.f, 0.f, 0.f, 0.f};
    f4 vq4 = {0.f, 0.f, 0.f, 0.f};
    #pragma unroll
    for (int k = 0; k < VH_SLICES; ++k) {
        vh4 += ((const f4*)(ws + WS_VHP + k * DD))[lane];
        vq4 += ((const f4*)(ws + WS_VQP + k * DD))[lane];
    }
    const f2 vpl = ((const f2*)(ws + WS_VP))[lane];

    // per-batch q scalar, computed redundantly per wave (cached reads)
    const float4 q4 = ((const float4*)(q + (size_t)b * DD))[lane];
    float qp = q4.x * vq4.x + q4.y * vq4.y + q4.z * vq4.z + q4.w * vq4.w;
    #pragma unroll
    for (int off = 32; off >= 1; off >>= 1) qp += __shfl_xor(qp, off, 64);
    const float qd = qp + ws[WS_BC];

    const int s0 = c * ROWS_PER_BLOCK + wave * ROWS_PER_WAVE;
    const f4*    hbase = (const f4*)(h + (size_t)b * SS * DD);
    const float* pfsel = ((lane < 32) ? pf1 : pf2) + (size_t)b * SS * DPP + 2 * ll;

    float  l = 0.f;
    float4 ctx = make_float4(0.f, 0.f, 0.f, 0.f);

    f4 hA[BATCH]; f2 pA[BATCH];
    f4 hB[BATCH]; f2 pB[BATCH];

    // ---- L0: load batch 0 into A ----
    #pragma unroll
    for (int j = 0; j < BATCH; ++j) {
        const int s = s0 + 0 * BATCH + j;
        hA[j] = __builtin_nontemporal_load(hbase + (size_t)s * (DD / 4) + lane);
        pA[j] = __builtin_nontemporal_load((const f2*)(pfsel + (size_t)s * DPP));
    }
    // ---- L1: load batch 1 into B ----
    #pragma unroll
    for (int j = 0; j < BATCH; ++j) {
        const int s = s0 + 1 * BATCH + j;
        hB[j] = __builtin_nontemporal_load(hbase + (size_t)s * (DD / 4) + lane);
        pB[j] = __builtin_nontemporal_load((const f2*)(pfsel + (size_t)s * DPP));
    }

    // ---- C0: compute A ----
    {
        float part[BATCH];
        #pragma unroll
        for (int j = 0; j < BATCH; ++j)
            part[j] = hA[j].x * vh4.x + hA[j].y * vh4.y
                    + hA[j].z * vh4.z + hA[j].w * vh4.w
                    + pA[j].x * vpl.x + pA[j].y * vpl.y;
        #pragma unroll
        for (int off = 32; off >= 1; off >>= 1) {
            #pragma unroll
            for (int j = 0; j < BATCH; ++j)
                part[j] += __shfl_xor(part[j], off, 64);
        }
        #pragma unroll
        for (int j = 0; j < BATCH; ++j) {
            const float score = part[j] + qd;
            const float e2 = __expf(2.f * score);
            const float t  = 1.f - 2.f * __builtin_amdgcn_rcpf(e2 + 1.f);
            const float w  = __expf(t);
            l += w;
            ctx.x += w * hA[j].x;
            ctx.y += w * hA[j].y;
            ctx.z += w * hA[j].z;
            ctx.w += w * hA[j].w;
        }
    }
    // ---- L2: load batch 2 into A ----
    #pragma unroll
    for (int j = 0; j < BATCH; ++j) {
        const int s = s0 + 2 * BATCH + j;
        hA[j] = __builtin_nontemporal_load(hbase + (size_t)s * (DD / 4) + lane);
        pA[j] = __builtin_nontemporal_load((const f2*)(pfsel + (size_t)s * DPP));
    }
    // ---- C1: compute B ----
    {
        float part[BATCH];
        #pragma unroll
        for (int j = 0; j < BATCH; ++j)
            part[j] = hB[j].x * vh4.x + hB[j].y * vh4.y
                    + hB[j].z * vh4.z + hB[j].w * vh4.w
                    + pB[j].x * vpl.x + pB[j].y * vpl.y;
        #pragma unroll
        for (int off = 32; off >= 1; off >>= 1) {
            #pragma unroll
            for (int j = 0; j < BATCH; ++j)
                part[j] += __shfl_xor(part[j], off, 64);
        }
        #pragma unroll
        for (int j = 0; j < BATCH; ++j) {
            const float score = part[j] + qd;
            const float e2 = __expf(2.f * score);
            const float t  = 1.f - 2.f * __builtin_amdgcn_rcpf(e2 + 1.f);
            const float w  = __expf(t);
            l += w;
            ctx.x += w * hB[j].x;
            ctx.y += w * hB[j].y;
            ctx.z += w * hB[j].z;
            ctx.w += w * hB[j].w;
        }
    }
    // ---- L3: load batch 3 into B ----
    #pragma unroll
    for (int j = 0; j < BATCH; ++j) {
        const int s = s0 + 3 * BATCH + j;
        hB[j] = __builtin_nontemporal_load(hbase + (size_t)s * (DD / 4) + lane);
        pB[j] = __builtin_nontemporal_load((const f2*)(pfsel + (size_t)s * DPP));
    }
    // ---- C2: compute A ----
    {
        float part[BATCH];
        #pragma unroll
        for (int j = 0; j < BATCH; ++j)
            part[j] = hA[j].x * vh4.x + hA[j].y * vh4.y
                    + hA[j].z * vh4.z + hA[j].w * vh4.w
                    + pA[j].x * vpl.x + pA[j].y * vpl.y;
        #pragma unroll
        for (int off = 32; off >= 1; off >>= 1) {
            #pragma unroll
            for (int j = 0; j < BATCH; ++j)
                part[j] += __shfl_xor(part[j], off, 64);
        }
        #pragma unroll
        for (int j = 0; j < BATCH; ++j) {
            const float score = part[j] + qd;
            const float e2 = __expf(2.f * score);
            const float t  = 1.f - 2.f * __builtin_amdgcn_rcpf(e2 + 1.f);
            const float w  = __expf(t);
            l += w;
            ctx.x += w * hA[j].x;
            ctx.y += w * hA[j].y;
            ctx.z += w * hA[j].z;
            ctx.w += w * hA[j].w;
        }
    }
    // ---- C3: compute B ----
    {
        float part[BATCH];
        #pragma unroll
        for (int j = 0; j < BATCH; ++j)
            part[j] = hB[j].x * vh4.x + hB[j].y * vh4.y
                    + hB[j].z * vh4.z + hB[j].w * vh4.w
                    + pB[j].x * vpl.x + pB[j].y * vpl.y;
        #pragma unroll
        for (int off = 32; off >= 1; off >>= 1) {
            #pragma unroll
            for (int j = 0; j < BATCH; ++j)
                part[j] += __shfl_xor(part[j], off, 64);
        }
        #pragma unroll
        for (int j = 0; j < BATCH; ++j) {
            const float score = part[j] + qd;
            const float e2 = __expf(2.f * score);
            const float t  = 1.f - 2.f * __builtin_amdgcn_rcpf(e2 + 1.f);
            const float w  = __expf(t);
            l += w;
            ctx.x += w * hB[j].x;
            ctx.y += w * hB[j].y;
            ctx.z += w * hB[j].z;
            ctx.w += w * hB[j].w;
        }
    }

    // combine the block's 4 waves in LDS, then one plain store per thread
    __shared__ float s_l[WAVES_PER_BLOCK];
    __shared__ float s_ctx[WAVES_PER_BLOCK][DD];
    if (lane == 0) s_l[wave] = l;
    ((float4*)s_ctx[wave])[lane] = ctx;
    __syncthreads();

    const float cd = s_ctx[0][tid] + s_ctx[1][tid] + s_ctx[2][tid] + s_ctx[3][tid];
    float* part_out = ws + WS_PART + (size_t)(b * CHUNKS + c) * PART_STRIDE;
    part_out[1 + tid] = cd;
    if (tid == 0) part_out[0] = s_l[0] + s_l[1] + s_l[2] + s_l[3];
}

// ---------------------------------------------------------------------------
// Kernel 2: merge the CHUNKS partials per batch, scale by 1/(L*S).
// ---------------------------------------------------------------------------
__global__ void finalize_kernel(const float* __restrict__ ws,
                                float* __restrict__ out) {
    const int b   = blockIdx.x;
    const int tid = threadIdx.x; // 256
    __shared__ float s_l[CHUNKS];
    const float* base = ws + WS_PART + (size_t)b * CHUNKS * PART_STRIDE;
    if (tid < CHUNKS) s_l[tid] = base[(size_t)tid * PART_STRIDE];
    __syncthreads();
    float L = 0.f, acc = 0.f;
    #pragma unroll 8
    for (int c = 0; c < CHUNKS; ++c) {
        L   += s_l[c];
        acc += base[(size_t)c * PART_STRIDE + 1 + tid];
    }
    out[b * DD + tid] = acc / (L * (float)SS);
}

extern "C" void kernel_launch(void* const* d_in, const int* in_sizes, int n_in,
                              void* d_out, int out_size, void* d_ws, size_t ws_size,
                              hipStream_t stream) {
    const float* h   = (const float*)d_in[0];
    const float* q   = (const float*)d_in[1];
    const float* pf1 = (const float*)d_in[2];
    const float* pf2 = (const float*)d_in[3];
    const float* Wh  = (const float*)d_in[4];
    const float* Wq  = (const float*)d_in[5];
    const float* Wp1 = (const float*)d_in[6];
    const float* Wp2 = (const float*)d_in[7];
    const float* Wc  = (const float*)d_in[8];
    const float* bc  = (const float*)d_in[9];
    float* out = (float*)d_out;
    float* ws  = (float*)d_ws;

    prep_kernel<<<VH_SLICES + 1, 256, 0, stream>>>(Wh, Wq, Wp1, Wp2, Wc, bc, ws);
    main_kernel<<<dim3(CHUNKS, BB), 256, 0, stream>>>(h, q, pf1, pf2, ws);
    finalize_kernel<<<BB, 256, 0, stream>>>(ws, out);
}

// Round 6
// 271.866 us; speedup vs baseline: 1.0413x; 1.0413x over previous
//
#include <hip/hip_runtime.h>
#include <math.h>

#define BB 32
#define SS 4096
#define DD 256
#define DAA 128
#define DPP 64
#define CHUNKS 32
#define ROWS_PER_BLOCK (SS / CHUNKS)                     // 128
#define WAVES_PER_BLOCK 4
#define ROWS_PER_WAVE (ROWS_PER_BLOCK / WAVES_PER_BLOCK) // 32
#define BATCH 4
#define NBATCH (ROWS_PER_WAVE / BATCH)                   // 8
#define VH_SLICES 8
#define SLICE (DAA / VH_SLICES)                          // 16

// workspace layout (float elements)
#define WS_VHP  0                         // 8 x 256 partial vh
#define WS_VQP  (WS_VHP + VH_SLICES*DD)   // 8 x 256 partial vq
#define WS_VP   (WS_VQP + VH_SLICES*DD)   // 128: [vp1[64] | vp2[64]]
#define WS_BC   (WS_VP + 128)
#define WS_PART (WS_BC + 16)              // 16B-aligned
#define PART_STRIDE 258                   // [l, ctx[256], pad]

typedef float f4 __attribute__((ext_vector_type(4)));
typedef float f2 __attribute__((ext_vector_type(2)));

// ---------------------------------------------------------------------------
// Kernel 0: fold Wc into projection vectors. Blocks 0..7 each do a 16-row
// slice of the Wh/Wq dots; block 8 does vp1/vp2/bc. main sums the 8
// partials per lane.
// ---------------------------------------------------------------------------
__global__ void prep_kernel(const float* __restrict__ Wh,
                            const float* __restrict__ Wq,
                            const float* __restrict__ Wp1,
                            const float* __restrict__ Wp2,
                            const float* __restrict__ Wc,
                            const float* __restrict__ bc,
                            float* __restrict__ ws) {
    const int tid = threadIdx.x; // 256 threads
    const int blk = blockIdx.x;
    if (blk < VH_SLICES) {
        const int a0 = blk * SLICE;
        float vh = 0.f, vq = 0.f;
        #pragma unroll
        for (int i = 0; i < SLICE; ++i) {
            const int a = a0 + i;
            vh += Wh[a * DD + tid] * Wc[a];
            vq += Wq[a * DD + tid] * Wc[DAA + a];
        }
        ws[WS_VHP + blk * DD + tid] = vh;
        ws[WS_VQP + blk * DD + tid] = vq;
    } else {
        if (tid < DPP) {
            float vp1 = 0.f, vp2 = 0.f;
            for (int a = 0; a < DPP; ++a) {
                vp1 += Wp1[a * DPP + tid] * Wc[2 * DAA + a];
                vp2 += Wp2[a * DPP + tid] * Wc[2 * DAA + DPP + a];
            }
            ws[WS_VP + tid]       = vp1;   // lanes 0..31 read pairs from here
            ws[WS_VP + DPP + tid] = vp2;   // lanes 32..63 read pairs from here
        }
        if (tid == 0) ws[WS_BC] = bc[0];
    }
}

// ---------------------------------------------------------------------------
// Kernel 1: streaming tanh-softmax context.
// R11: double-buffer with NAMED SCALARS ONLY. R5 proved even straight-line
// code with arrays fails: #pragma-unroll indices are runtime at SROA time,
// so arrays rely on backend PromoteAlloca, whose budget rejects the
// 96-float two-buffer footprint (VGPR=64, 94MB scratch in R2/R3/R5;
// the 56-float single-buffer of R1/R4 fits). Named f4/f2 locals are SSA
// values -- no alloca exists, promotion cannot fail. BATCH=4 x2 buffers
// = 48 VGPRs, peak live ~90, under the 128 cap of (256,4). Macros expand
// to pure straight-line code (no loops/pragmas inside). Grid 1024 =
// 4 blocks/CU, same residency as R4 -> delta attributable to pipeline.
// Bulk reads nontemporal. No __threadfence.
// ---------------------------------------------------------------------------
#define LOAD4(H0, H1, H2, H3, P0, P1, P2, P3, IB)                              \
    H0 = __builtin_nontemporal_load(hbase + (size_t)(s0 + (IB)*BATCH + 0) * (DD/4) + lane); \
    P0 = __builtin_nontemporal_load((const f2*)(pfsel + (size_t)(s0 + (IB)*BATCH + 0) * DPP)); \
    H1 = __builtin_nontemporal_load(hbase + (size_t)(s0 + (IB)*BATCH + 1) * (DD/4) + lane); \
    P1 = __builtin_nontemporal_load((const f2*)(pfsel + (size_t)(s0 + (IB)*BATCH + 1) * DPP)); \
    H2 = __builtin_nontemporal_load(hbase + (size_t)(s0 + (IB)*BATCH + 2) * (DD/4) + lane); \
    P2 = __builtin_nontemporal_load((const f2*)(pfsel + (size_t)(s0 + (IB)*BATCH + 2) * DPP)); \
    H3 = __builtin_nontemporal_load(hbase + (size_t)(s0 + (IB)*BATCH + 3) * (DD/4) + lane); \
    P3 = __builtin_nontemporal_load((const f2*)(pfsel + (size_t)(s0 + (IB)*BATCH + 3) * DPP));

#define DOT(H, P) ((H).x * vh4.x + (H).y * vh4.y + (H).z * vh4.z + (H).w * vh4.w \
                 + (P).x * vpl.x + (P).y * vpl.y)

#define BFLY(OFF)                                                              \
    r0 += __shfl_xor(r0, OFF, 64);                                             \
    r1 += __shfl_xor(r1, OFF, 64);                                             \
    r2 += __shfl_xor(r2, OFF, 64);                                             \
    r3 += __shfl_xor(r3, OFF, 64);

#define FIN(H, R)                                                              \
    {                                                                          \
        const float score_ = (R) + qd;                                         \
        const float e2_ = __expf(2.f * score_);                                \
        const float t_  = 1.f - 2.f * __builtin_amdgcn_rcpf(e2_ + 1.f);        \
        const float w_  = __expf(t_);                                          \
        l += w_;                                                               \
        ctx.x += w_ * (H).x;                                                   \
        ctx.y += w_ * (H).y;                                                   \
        ctx.z += w_ * (H).z;                                                   \
        ctx.w += w_ * (H).w;                                                   \
    }

#define COMPUTE4(H0, H1, H2, H3, P0, P1, P2, P3)                               \
    {                                                                          \
        float r0 = DOT(H0, P0);                                                \
        float r1 = DOT(H1, P1);                                                \
        float r2 = DOT(H2, P2);                                                \
        float r3 = DOT(H3, P3);                                                \
        BFLY(32) BFLY(16) BFLY(8) BFLY(4) BFLY(2) BFLY(1)                      \
        FIN(H0, r0) FIN(H1, r1) FIN(H2, r2) FIN(H3, r3)                        \
    }

__global__ __launch_bounds__(256, 4) void
main_kernel(const float* __restrict__ h,
            const float* __restrict__ q,
            const float* __restrict__ pf1,
            const float* __restrict__ pf2,
            float* __restrict__ ws) {
    const int c    = blockIdx.x;
    const int b    = blockIdx.y;
    const int tid  = threadIdx.x;
    const int wave = tid >> 6;
    const int lane = tid & 63;
    const int ll   = lane & 31;

    // per-lane constants: sum the 8 prep partials (L2-hot)
    f4 vh4 = {0.f, 0.f, 0.f, 0.f};
    f4 vq4 = {0.f, 0.f, 0.f, 0.f};
    #pragma unroll
    for (int k = 0; k < VH_SLICES; ++k) {
        vh4 += ((const f4*)(ws + WS_VHP + k * DD))[lane];
        vq4 += ((const f4*)(ws + WS_VQP + k * DD))[lane];
    }
    const f2 vpl = ((const f2*)(ws + WS_VP))[lane];

    // per-batch q scalar, computed redundantly per wave (cached reads)
    const float4 q4 = ((const float4*)(q + (size_t)b * DD))[lane];
    float qp = q4.x * vq4.x + q4.y * vq4.y + q4.z * vq4.z + q4.w * vq4.w;
    #pragma unroll
    for (int off = 32; off >= 1; off >>= 1) qp += __shfl_xor(qp, off, 64);
    const float qd = qp + ws[WS_BC];

    const int s0 = c * ROWS_PER_BLOCK + wave * ROWS_PER_WAVE;
    const f4*    hbase = (const f4*)(h + (size_t)b * SS * DD);
    const float* pfsel = ((lane < 32) ? pf1 : pf2) + (size_t)b * SS * DPP + 2 * ll;

    float  l = 0.f;
    float4 ctx = make_float4(0.f, 0.f, 0.f, 0.f);

    // double-buffered pipeline over NBATCH=8, all state in named SSA vars
    f4 hA0, hA1, hA2, hA3, hB0, hB1, hB2, hB3;
    f2 pA0, pA1, pA2, pA3, pB0, pB1, pB2, pB3;

    LOAD4(hA0, hA1, hA2, hA3, pA0, pA1, pA2, pA3, 0)
    LOAD4(hB0, hB1, hB2, hB3, pB0, pB1, pB2, pB3, 1)
    COMPUTE4(hA0, hA1, hA2, hA3, pA0, pA1, pA2, pA3)
    LOAD4(hA0, hA1, hA2, hA3, pA0, pA1, pA2, pA3, 2)
    COMPUTE4(hB0, hB1, hB2, hB3, pB0, pB1, pB2, pB3)
    LOAD4(hB0, hB1, hB2, hB3, pB0, pB1, pB2, pB3, 3)
    COMPUTE4(hA0, hA1, hA2, hA3, pA0, pA1, pA2, pA3)
    LOAD4(hA0, hA1, hA2, hA3, pA0, pA1, pA2, pA3, 4)
    COMPUTE4(hB0, hB1, hB2, hB3, pB0, pB1, pB2, pB3)
    LOAD4(hB0, hB1, hB2, hB3, pB0, pB1, pB2, pB3, 5)
    COMPUTE4(hA0, hA1, hA2, hA3, pA0, pA1, pA2, pA3)
    LOAD4(hA0, hA1, hA2, hA3, pA0, pA1, pA2, pA3, 6)
    COMPUTE4(hB0, hB1, hB2, hB3, pB0, pB1, pB2, pB3)
    LOAD4(hB0, hB1, hB2, hB3, pB0, pB1, pB2, pB3, 7)
    COMPUTE4(hA0, hA1, hA2, hA3, pA0, pA1, pA2, pA3)
    COMPUTE4(hB0, hB1, hB2, hB3, pB0, pB1, pB2, pB3)

    // combine the block's 4 waves in LDS, then one plain store per thread
    __shared__ float s_l[WAVES_PER_BLOCK];
    __shared__ float s_ctx[WAVES_PER_BLOCK][DD];
    if (lane == 0) s_l[wave] = l;
    ((float4*)s_ctx[wave])[lane] = ctx;
    __syncthreads();

    const float cd = s_ctx[0][tid] + s_ctx[1][tid] + s_ctx[2][tid] + s_ctx[3][tid];
    float* part_out = ws + WS_PART + (size_t)(b * CHUNKS + c) * PART_STRIDE;
    part_out[1 + tid] = cd;
    if (tid == 0) part_out[0] = s_l[0] + s_l[1] + s_l[2] + s_l[3];
}

// ---------------------------------------------------------------------------
// Kernel 2: merge the CHUNKS partials per batch, scale by 1/(L*S).
// ---------------------------------------------------------------------------
__global__ void finalize_kernel(const float* __restrict__ ws,
                                float* __restrict__ out) {
    const int b   = blockIdx.x;
    const int tid = threadIdx.x; // 256
    __shared__ float s_l[CHUNKS];
    const float* base = ws + WS_PART + (size_t)b * CHUNKS * PART_STRIDE;
    if (tid < CHUNKS) s_l[tid] = base[(size_t)tid * PART_STRIDE];
    __syncthreads();
    float L = 0.f, acc = 0.f;
    #pragma unroll 8
    for (int c = 0; c < CHUNKS; ++c) {
        L   += s_l[c];
        acc += base[(size_t)c * PART_STRIDE + 1 + tid];
    }
    out[b * DD + tid] = acc / (L * (float)SS);
}

extern "C" void kernel_launch(void* const* d_in, const int* in_sizes, int n_in,
                              void* d_out, int out_size, void* d_ws, size_t ws_size,
                              hipStream_t stream) {
    const float* h   = (const float*)d_in[0];
    const float* q   = (const float*)d_in[1];
    const float* pf1 = (const float*)d_in[2];
    const float* pf2 = (const float*)d_in[3];
    const float* Wh  = (const float*)d_in[4];
    const float* Wq  = (const float*)d_in[5];
    const float* Wp1 = (const float*)d_in[6];
    const float* Wp2 = (const float*)d_in[7];
    const float* Wc  = (const float*)d_in[8];
    const float* bc  = (const float*)d_in[9];
    float* out = (float*)d_out;
    float* ws  = (float*)d_ws;

    prep_kernel<<<VH_SLICES + 1, 256, 0, stream>>>(Wh, Wq, Wp1, Wp2, Wc, bc, ws);
    main_kernel<<<dim3(CHUNKS, BB), 256, 0, stream>>>(h, q, pf1, pf2, ws);
    finalize_kernel<<<BB, 256, 0, stream>>>(ws, out);
}